// Round 1
// baseline (2081.769 us; speedup 1.0000x reference)
//
#include <hip/hip_runtime.h>

#define H 128

struct NetParams { const float *Win, *bi, *Wh, *bh, *Wout, *bo; };

// ---------------- tanh jet composition (Faa di Bruno) ----------------
// JET=1 : [u]
// JET=5 : [u, ux, uxx, uy, uyy]          (two independent directional 2-jets)
// JET=10: [u, ux, uy, uxx, uxy, uyy, uxxx, uxxy, uxyy, uyyy]
template<int JET>
__device__ inline void tanh_jet(const float* z, float* o) {
  float t  = tanhf(z[0]);
  float t1 = 1.0f - t * t;          // t'
  o[0] = t;
  if constexpr (JET >= 5) {
    float t2 = -2.0f * t * t1;      // t''
    if constexpr (JET == 5) {
      o[1] = t1 * z[1];
      o[2] = t2 * z[1] * z[1] + t1 * z[2];
      o[3] = t1 * z[3];
      o[4] = t2 * z[3] * z[3] + t1 * z[4];
    } else { // JET == 10
      float t3 = t1 * (6.0f * t * t - 2.0f);   // t'''
      float zx = z[1], zy = z[2], zxx = z[3], zxy = z[4], zyy = z[5];
      o[1] = t1 * zx;
      o[2] = t1 * zy;
      o[3] = t2 * zx * zx + t1 * zxx;
      o[4] = t2 * zx * zy + t1 * zxy;
      o[5] = t2 * zy * zy + t1 * zyy;
      o[6] = t3 * zx * zx * zx + 3.0f * t2 * zx * zxx + t1 * z[6];
      o[7] = t3 * zx * zx * zy + t2 * (zxx * zy + 2.0f * zxy * zx) + t1 * z[7];
      o[8] = t3 * zx * zy * zy + t2 * (zyy * zx + 2.0f * zxy * zy) + t1 * z[8];
      o[9] = t3 * zy * zy * zy + 3.0f * t2 * zy * zyy + t1 * z[9];
    }
  }
}

// ---------------- LDS jet storage (aligned split regions) ----------------
// X layout: region A: float4[H*PTS], region B: float4[H*PTS] (JET=10),
//           tail: float[H*PTS] (JET=5) or float2[H*PTS] (JET=10).
template<int JET, int PTS>
__device__ inline void x_read(const float* X, int k, int p, float* v) {
  int idx = k * PTS + p;
  if constexpr (JET == 1) {
    v[0] = X[idx];
  } else if constexpr (JET == 5) {
    float4 a = ((const float4*)X)[idx];
    v[0] = a.x; v[1] = a.y; v[2] = a.z; v[3] = a.w;
    v[4] = (X + H * PTS * 4)[idx];
  } else {
    float4 a = ((const float4*)X)[idx];
    float4 b = ((const float4*)(X + H * PTS * 4))[idx];
    float2 c = ((const float2*)(X + H * PTS * 8))[idx];
    v[0] = a.x; v[1] = a.y; v[2] = a.z; v[3] = a.w;
    v[4] = b.x; v[5] = b.y; v[6] = b.z; v[7] = b.w;
    v[8] = c.x; v[9] = c.y;
  }
}

template<int JET, int PTS>
__device__ inline void x_write(float* X, int k, int p, const float* v) {
  int idx = k * PTS + p;
  if constexpr (JET == 1) {
    X[idx] = v[0];
  } else if constexpr (JET == 5) {
    ((float4*)X)[idx] = make_float4(v[0], v[1], v[2], v[3]);
    (X + H * PTS * 4)[idx] = v[4];
  } else {
    ((float4*)X)[idx] = make_float4(v[0], v[1], v[2], v[3]);
    ((float4*)(X + H * PTS * 4))[idx] = make_float4(v[4], v[5], v[6], v[7]);
    ((float2*)(X + H * PTS * 8))[idx] = make_float2(v[8], v[9]);
  }
}

// ---------------- full network jet evaluation ----------------
// Block: PTS points, 16 j-groups of 8 output neurons each. threads = PTS*16.
// ldsX: H*PTS*JET floats. ldsW: 4096 floats (32-row weight chunk; also reused
// as output-reduction scratch). U: PTS*JET floats result (all threads see it).
template<int JET, int PTS>
__device__ void eval_net(const NetParams& P, float x, float y,
                         float* ldsX, float* ldsW, float* U) {
  const int t = threadIdx.x;
  constexpr int NT = PTS * 16;
  const int p = t % PTS;
  const int g = t / PTS;

  // ---- input layer: z = x*Win[0][j] + y*Win[1][j] + bi[j]
  {
    const float4* Wi0 = (const float4*)(P.Win);
    const float4* Wi1 = (const float4*)(P.Win + H);
    const float4* Bi  = (const float4*)(P.bi);
    float4 a0 = Wi0[g * 2], a1 = Wi0[g * 2 + 1];
    float4 b0 = Wi1[g * 2], b1 = Wi1[g * 2 + 1];
    float4 c0 = Bi[g * 2],  c1 = Bi[g * 2 + 1];
    float w0v[8] = {a0.x, a0.y, a0.z, a0.w, a1.x, a1.y, a1.z, a1.w};
    float w1v[8] = {b0.x, b0.y, b0.z, b0.w, b1.x, b1.y, b1.z, b1.w};
    float bv[8]  = {c0.x, c0.y, c0.z, c0.w, c1.x, c1.y, c1.z, c1.w};
#pragma unroll
    for (int jj = 0; jj < 8; jj++) {
      float z[JET];
#pragma unroll
      for (int q = 0; q < JET; q++) z[q] = 0.0f;
      z[0] = x * w0v[jj] + y * w1v[jj] + bv[jj];
      if constexpr (JET == 5)  { z[1] = w0v[jj]; z[3] = w1v[jj]; }
      if constexpr (JET == 10) { z[1] = w0v[jj]; z[2] = w1v[jj]; }
      float o[JET];
      tanh_jet<JET>(z, o);
      x_write<JET, PTS>(ldsX, g * 8 + jj, p, o);
    }
  }
  __syncthreads();

  // ---- 3 hidden layers
  for (int l = 0; l < 3; l++) {
    const float* W = P.Wh + l * H * H;
    float acc[8][JET];
#pragma unroll
    for (int jj = 0; jj < 8; jj++)
#pragma unroll
      for (int q = 0; q < JET; q++) acc[jj][q] = 0.0f;

    for (int c = 0; c < 4; c++) {   // 4 chunks of 32 weight rows
      __syncthreads();              // previous chunk fully consumed
      {
        const float4* Wg = (const float4*)(W + c * 32 * H);
        float4* Wl = (float4*)ldsW;
#pragma unroll
        for (int i = 0; i < 1024 / NT; i++) Wl[t + i * NT] = Wg[t + i * NT];
      }
      __syncthreads();
      for (int kk = 0; kk < 32; kk++) {
        float xv[JET];
        x_read<JET, PTS>(ldsX, c * 32 + kk, p, xv);
        const float4* Wl4 = (const float4*)ldsW;
        float4 wa = Wl4[kk * 32 + g * 2];
        float4 wb = Wl4[kk * 32 + g * 2 + 1];
        float wv[8] = {wa.x, wa.y, wa.z, wa.w, wb.x, wb.y, wb.z, wb.w};
#pragma unroll
        for (int jj = 0; jj < 8; jj++)
#pragma unroll
          for (int q = 0; q < JET; q++)
            acc[jj][q] = fmaf(wv[jj], xv[q], acc[jj][q]);
      }
    }
    __syncthreads();  // all ldsX reads done before in-place overwrite
    const float* bhl = P.bh + l * H;
#pragma unroll
    for (int jj = 0; jj < 8; jj++) {
      float z[JET];
#pragma unroll
      for (int q = 0; q < JET; q++) z[q] = acc[jj][q];
      z[0] += bhl[g * 8 + jj];
      float o[JET];
      tanh_jet<JET>(z, o);
      x_write<JET, PTS>(ldsX, g * 8 + jj, p, o);
    }
    __syncthreads();
  }

  // ---- output layer: u = sum_k h[k] * Wout[k] + bo
  {
    float pacc[JET];
#pragma unroll
    for (int q = 0; q < JET; q++) pacc[q] = 0.0f;
    const float4* Wo = (const float4*)P.Wout;
    float4 wa = Wo[g * 2], wb = Wo[g * 2 + 1];
    float wv[8] = {wa.x, wa.y, wa.z, wa.w, wb.x, wb.y, wb.z, wb.w};
#pragma unroll
    for (int kk = 0; kk < 8; kk++) {
      float xv[JET];
      x_read<JET, PTS>(ldsX, g * 8 + kk, p, xv);
#pragma unroll
      for (int q = 0; q < JET; q++) pacc[q] = fmaf(wv[kk], xv[q], pacc[q]);
    }
    float* R = ldsW;  // reuse: [16][PTS][JET] <= 2560 floats < 4096
#pragma unroll
    for (int q = 0; q < JET; q++) R[(g * PTS + p) * JET + q] = pacc[q];
    __syncthreads();
    if (t < PTS * JET) {
      int pp = t % PTS, q = t / PTS;
      float s = 0.0f;
#pragma unroll
      for (int gg = 0; gg < 16; gg++) s += R[(gg * PTS + pp) * JET + q];
      if (q == 0) s += P.bo[0];
      U[pp * JET + q] = s;
    }
    __syncthreads();
  }
}

// ---------------- kernels ----------------
// ws layout (floats): [0,2048) res1 | [2048,4096) res2 | [4096,4352) bnd1 |
// [4352,4608) bnd2 | [4608, 4608+9*512) interface terms (term-major).
#define WS_RES1 0
#define WS_RES2 2048
#define WS_BND1 4096
#define WS_BND2 4352
#define WS_INTF 4608

__global__ void __launch_bounds__(256) residual_kernel(
    const float* xf1, const float* yf1, const float* ff1,
    const float* xf2, const float* yf2, const float* ff2,
    NetParams P1, NetParams P2, float* ws) {
  constexpr int JET = 5, PTS = 16;
  __shared__ __align__(16) float ldsX[H * PTS * JET];
  __shared__ __align__(16) float ldsW[4096];
  __shared__ float U[PTS * JET];
  __shared__ float T[PTS];
  const int t = threadIdx.x;
  const int p = t % PTS;
  const int net = blockIdx.y;
  const float* xs = net ? xf2 : xf1;
  const float* ys = net ? yf2 : yf1;
  const float* fs = net ? ff2 : ff1;
  NetParams P = net ? P2 : P1;
  const int base = blockIdx.x * PTS;
  float x = xs[base + p], y = ys[base + p];
  eval_net<JET, PTS>(P, x, y, ldsX, ldsW, U);
  if (t < PTS) {
    float f = U[t * JET + 2] + U[t * JET + 4] - fs[base + t];  // uxx+uyy-ff
    T[t] = f * f;
  }
  __syncthreads();
  if (t == 0) {
    float s = 0.0f;
#pragma unroll
    for (int i = 0; i < PTS; i++) s += T[i];
    ws[(net ? WS_RES2 : WS_RES1) + blockIdx.x] = s;
  }
}

__global__ void __launch_bounds__(256) boundary_kernel(
    const float* xb1, const float* yb1, const float* ub1,
    const float* xb2, const float* yb2, const float* ub2,
    NetParams P1, NetParams P2, float* ws) {
  constexpr int JET = 1, PTS = 16;
  __shared__ __align__(16) float ldsX[H * PTS * JET];
  __shared__ __align__(16) float ldsW[4096];
  __shared__ float U[PTS * JET];
  __shared__ float T[PTS];
  const int t = threadIdx.x;
  const int p = t % PTS;
  const int net = blockIdx.y;
  const float* xs = net ? xb2 : xb1;
  const float* ys = net ? yb2 : yb1;
  const float* us = net ? ub2 : ub1;
  NetParams P = net ? P2 : P1;
  const int base = blockIdx.x * PTS;
  float x = xs[base + p], y = ys[base + p];
  eval_net<JET, PTS>(P, x, y, ldsX, ldsW, U);
  if (t < PTS) {
    float d = us[base + t] - U[t];
    T[t] = d * d;
  }
  __syncthreads();
  if (t == 0) {
    float s = 0.0f;
#pragma unroll
    for (int i = 0; i < PTS; i++) s += T[i];
    ws[(net ? WS_BND2 : WS_BND1) + blockIdx.x] = s;
  }
}

__global__ void __launch_bounds__(128) interface_kernel(
    const float* xi, const float* yi, const float* fi,
    NetParams P1, NetParams P2, float* ws) {
  constexpr int JET = 10, PTS = 8;
  __shared__ __align__(16) float ldsX[H * PTS * JET];
  __shared__ __align__(16) float ldsW[4096];
  __shared__ float U1[PTS * JET];
  __shared__ float U2[PTS * JET];
  __shared__ float T[PTS * 9];
  const int t = threadIdx.x;
  const int p = t % PTS;
  const int base = blockIdx.x * PTS;
  float x = xi[base + p], y = yi[base + p];
  eval_net<JET, PTS>(P1, x, y, ldsX, ldsW, U1);
  eval_net<JET, PTS>(P2, x, y, ldsX, ldsW, U2);
  if (t < PTS) {
    const float* a = U1 + t * JET;
    const float* b = U2 + t * JET;
    float fsrc = fi[base + t];
    float f1 = a[3] + a[5] - fsrc;           // v1xx+v1yy-fi
    float f2 = b[3] + b[5] - fsrc;
    float du = a[0] - b[0];
    float fd = f1 - f2;
    float dfl = a[2] - b[2];                 // v1y - v2y
    float g1x = a[6] + a[8], g1y = a[7] + a[9];
    float g2x = b[6] + b[8], g2y = b[7] + b[9];
    float dyy = a[5] - b[5];
    float dx  = a[1] - b[1];
    float dxx = a[3] - b[3];
    T[t * 9 + 0] = du * du;
    T[t * 9 + 1] = f1 * f1;
    T[t * 9 + 2] = f2 * f2;
    T[t * 9 + 3] = fd * fd;
    T[t * 9 + 4] = dfl * dfl;
    T[t * 9 + 5] = g1x * g1x + g1y * g1y + g2x * g2x + g2y * g2y;
    T[t * 9 + 6] = dyy * dyy;
    T[t * 9 + 7] = dx * dx;
    T[t * 9 + 8] = dxx * dxx;
  }
  __syncthreads();
  if (t < 9) {
    float s = 0.0f;
#pragma unroll
    for (int i = 0; i < PTS; i++) s += T[i * 9 + t];
    ws[WS_INTF + t * 512 + blockIdx.x] = s;
  }
}

__global__ void __launch_bounds__(256) combine_kernel(
    const float* ws, const float* iw, float* out) {
  __shared__ float red[256];
  __shared__ float sums[13];
  const int t = threadIdx.x;
  const int off[13] = {WS_RES1, WS_RES2, WS_BND1, WS_BND2,
                       WS_INTF + 0 * 512, WS_INTF + 1 * 512, WS_INTF + 2 * 512,
                       WS_INTF + 3 * 512, WS_INTF + 4 * 512, WS_INTF + 5 * 512,
                       WS_INTF + 6 * 512, WS_INTF + 7 * 512, WS_INTF + 8 * 512};
  const int len[13] = {2048, 2048, 256, 256, 512, 512, 512, 512, 512, 512, 512, 512, 512};
  for (int r = 0; r < 13; r++) {
    float s = 0.0f;
    for (int i = t; i < len[r]; i += 256) s += ws[off[r] + i];
    red[t] = s;
    __syncthreads();
    for (int w = 128; w > 0; w >>= 1) {
      if (t < w) red[t] += red[t + w];
      __syncthreads();
    }
    if (t == 0) sums[r] = red[0];
    __syncthreads();
  }
  if (t == 0) {
    const float Nf = 32768.0f, Nb = 4096.0f, Ni = 4096.0f;
    float mse_f  = (sums[0] + sums[1]) / Nf;
    float mse_ub = (sums[2] + sums[3]) / Nb;
    float su = sums[4];
    float mse_i_u    = su / Ni;
    float mse_i_uavg = su / (2.0f * Ni);
    float mse_i_res  = (sums[5] + sums[6]) / Ni;
    float mse_cont   = sums[7] / Ni;
    float mse_flux   = sums[8] / Ni;
    float mse_gres   = sums[9] / Ni;
    float mse_uyy    = sums[10] / Ni;
    float mse_ux     = sums[11] / Ni;
    float mse_uxx    = sums[12] / Ni;
    float il = iw[0] * mse_i_u + iw[1] * mse_i_uavg + iw[2] * mse_i_res
             + iw[3] * mse_cont + iw[4] * mse_flux + iw[6] * mse_gres
             + iw[5] * mse_uyy + iw[7] * mse_ux + iw[8] * mse_uxx;
    out[0] = 20.0f * mse_ub + mse_f + 5.0f * il;
  }
}

extern "C" void kernel_launch(void* const* d_in, const int* in_sizes, int n_in,
                              void* d_out, int out_size, void* d_ws, size_t ws_size,
                              hipStream_t stream) {
  const float* xb1 = (const float*)d_in[0];
  const float* yb1 = (const float*)d_in[1];
  const float* ub1 = (const float*)d_in[2];
  const float* xb2 = (const float*)d_in[3];
  const float* yb2 = (const float*)d_in[4];
  const float* ub2 = (const float*)d_in[5];
  const float* xf1 = (const float*)d_in[6];
  const float* yf1 = (const float*)d_in[7];
  const float* ff1 = (const float*)d_in[8];
  const float* xf2 = (const float*)d_in[9];
  const float* yf2 = (const float*)d_in[10];
  const float* ff2 = (const float*)d_in[11];
  const float* xi1 = (const float*)d_in[12];
  const float* yi1 = (const float*)d_in[13];
  const float* fi1 = (const float*)d_in[14];
  const float* iw  = (const float*)d_in[15];
  NetParams P1 = {(const float*)d_in[16], (const float*)d_in[17],
                  (const float*)d_in[18], (const float*)d_in[19],
                  (const float*)d_in[20], (const float*)d_in[21]};
  NetParams P2 = {(const float*)d_in[22], (const float*)d_in[23],
                  (const float*)d_in[24], (const float*)d_in[25],
                  (const float*)d_in[26], (const float*)d_in[27]};
  float* ws = (float*)d_ws;
  float* out = (float*)d_out;

  dim3 gridR(2048, 2);
  hipLaunchKernelGGL(residual_kernel, gridR, dim3(256), 0, stream,
                     xf1, yf1, ff1, xf2, yf2, ff2, P1, P2, ws);
  dim3 gridB(256, 2);
  hipLaunchKernelGGL(boundary_kernel, gridB, dim3(256), 0, stream,
                     xb1, yb1, ub1, xb2, yb2, ub2, P1, P2, ws);
  hipLaunchKernelGGL(interface_kernel, dim3(512), dim3(128), 0, stream,
                     xi1, yi1, fi1, P1, P2, ws);
  hipLaunchKernelGGL(combine_kernel, dim3(1), dim3(256), 0, stream,
                     ws, iw, out);
}

// Round 2
// 733.936 us; speedup vs baseline: 2.8364x; 2.8364x over previous
//
#include <hip/hip_runtime.h>

#define H 128

struct NetParams { const float *Win, *bi, *Wh, *bh, *Wout, *bo; };

// ---------------- tanh jet composition (Faa di Bruno) ----------------
// JET=1 : [u]
// JET=5 : [u, ux, uxx, uy, uyy]          (two independent directional 2-jets)
// JET=10: [u, ux, uy, uxx, uxy, uyy, uxxx, uxxy, uxyy, uyyy]
template<int JET>
__device__ inline void tanh_jet(const float* z, float* o) {
  float t  = tanhf(z[0]);
  float t1 = 1.0f - t * t;          // t'
  o[0] = t;
  if constexpr (JET >= 5) {
    float t2 = -2.0f * t * t1;      // t''
    if constexpr (JET == 5) {
      o[1] = t1 * z[1];
      o[2] = t2 * z[1] * z[1] + t1 * z[2];
      o[3] = t1 * z[3];
      o[4] = t2 * z[3] * z[3] + t1 * z[4];
    } else { // JET == 10
      float t3 = t1 * (6.0f * t * t - 2.0f);   // t'''
      float zx = z[1], zy = z[2], zxx = z[3], zxy = z[4], zyy = z[5];
      o[1] = t1 * zx;
      o[2] = t1 * zy;
      o[3] = t2 * zx * zx + t1 * zxx;
      o[4] = t2 * zx * zy + t1 * zxy;
      o[5] = t2 * zy * zy + t1 * zyy;
      o[6] = t3 * zx * zx * zx + 3.0f * t2 * zx * zxx + t1 * z[6];
      o[7] = t3 * zx * zx * zy + t2 * (zxx * zy + 2.0f * zxy * zx) + t1 * z[7];
      o[8] = t3 * zx * zy * zy + t2 * (zyy * zx + 2.0f * zxy * zy) + t1 * z[8];
      o[9] = t3 * zy * zy * zy + 3.0f * t2 * zy * zyy + t1 * z[9];
    }
  }
}

// ---------------- LDS jet storage (aligned split regions) ----------------
template<int JET, int PTS>
__device__ inline void x_read(const float* X, int k, int p, float* v) {
  int idx = k * PTS + p;
  if constexpr (JET == 1) {
    v[0] = X[idx];
  } else if constexpr (JET == 5) {
    float4 a = ((const float4*)X)[idx];
    v[0] = a.x; v[1] = a.y; v[2] = a.z; v[3] = a.w;
    v[4] = (X + H * PTS * 4)[idx];
  } else {
    float4 a = ((const float4*)X)[idx];
    float4 b = ((const float4*)(X + H * PTS * 4))[idx];
    float2 c = ((const float2*)(X + H * PTS * 8))[idx];
    v[0] = a.x; v[1] = a.y; v[2] = a.z; v[3] = a.w;
    v[4] = b.x; v[5] = b.y; v[6] = b.z; v[7] = b.w;
    v[8] = c.x; v[9] = c.y;
  }
}

template<int JET, int PTS>
__device__ inline void x_write(float* X, int k, int p, const float* v) {
  int idx = k * PTS + p;
  if constexpr (JET == 1) {
    X[idx] = v[0];
  } else if constexpr (JET == 5) {
    ((float4*)X)[idx] = make_float4(v[0], v[1], v[2], v[3]);
    (X + H * PTS * 4)[idx] = v[4];
  } else {
    ((float4*)X)[idx] = make_float4(v[0], v[1], v[2], v[3]);
    ((float4*)(X + H * PTS * 4))[idx] = make_float4(v[4], v[5], v[6], v[7]);
    ((float2*)(X + H * PTS * 8))[idx] = make_float2(v[8], v[9]);
  }
}

// ---------------- full network jet evaluation ----------------
// Block: PTS points, 16 j-groups of 8 output neurons each. threads = PTS*16.
template<int JET, int PTS>
__device__ void eval_net(const NetParams& P, float x, float y,
                         float* ldsX, float* ldsW, float* U) {
  const int t = threadIdx.x;
  constexpr int NT = PTS * 16;
  const int p = t % PTS;
  const int g = t / PTS;

  // ---- input layer: z = x*Win[0][j] + y*Win[1][j] + bi[j]
  {
    const float4* Wi0 = (const float4*)(P.Win);
    const float4* Wi1 = (const float4*)(P.Win + H);
    const float4* Bi  = (const float4*)(P.bi);
    float4 a0 = Wi0[g * 2], a1 = Wi0[g * 2 + 1];
    float4 b0 = Wi1[g * 2], b1 = Wi1[g * 2 + 1];
    float4 c0 = Bi[g * 2],  c1 = Bi[g * 2 + 1];
    float w0v[8] = {a0.x, a0.y, a0.z, a0.w, a1.x, a1.y, a1.z, a1.w};
    float w1v[8] = {b0.x, b0.y, b0.z, b0.w, b1.x, b1.y, b1.z, b1.w};
    float bv[8]  = {c0.x, c0.y, c0.z, c0.w, c1.x, c1.y, c1.z, c1.w};
#pragma unroll
    for (int jj = 0; jj < 8; jj++) {
      float z[JET];
#pragma unroll
      for (int q = 0; q < JET; q++) z[q] = 0.0f;
      z[0] = x * w0v[jj] + y * w1v[jj] + bv[jj];
      if constexpr (JET == 5)  { z[1] = w0v[jj]; z[3] = w1v[jj]; }
      if constexpr (JET == 10) { z[1] = w0v[jj]; z[2] = w1v[jj]; }
      float o[JET];
      tanh_jet<JET>(z, o);
      x_write<JET, PTS>(ldsX, g * 8 + jj, p, o);
    }
  }
  __syncthreads();

  // ---- 3 hidden layers
  for (int l = 0; l < 3; l++) {
    const float* W = P.Wh + l * H * H;
    float acc[8][JET];
#pragma unroll
    for (int jj = 0; jj < 8; jj++)
#pragma unroll
      for (int q = 0; q < JET; q++) acc[jj][q] = 0.0f;

    for (int c = 0; c < 4; c++) {   // 4 chunks of 32 weight rows
      __syncthreads();              // previous chunk fully consumed
      {
        const float4* Wg = (const float4*)(W + c * 32 * H);
        float4* Wl = (float4*)ldsW;
#pragma unroll
        for (int i = 0; i < 1024 / NT; i++) Wl[t + i * NT] = Wg[t + i * NT];
      }
      __syncthreads();
      for (int kk = 0; kk < 32; kk++) {
        float xv[JET];
        x_read<JET, PTS>(ldsX, c * 32 + kk, p, xv);
        const float4* Wl4 = (const float4*)ldsW;
        float4 wa = Wl4[kk * 32 + g * 2];
        float4 wb = Wl4[kk * 32 + g * 2 + 1];
        float wv[8] = {wa.x, wa.y, wa.z, wa.w, wb.x, wb.y, wb.z, wb.w};
#pragma unroll
        for (int jj = 0; jj < 8; jj++)
#pragma unroll
          for (int q = 0; q < JET; q++)
            acc[jj][q] = fmaf(wv[jj], xv[q], acc[jj][q]);
      }
    }
    __syncthreads();  // all ldsX reads done before in-place overwrite
    const float* bhl = P.bh + l * H;
#pragma unroll
    for (int jj = 0; jj < 8; jj++) {
      float z[JET];
#pragma unroll
      for (int q = 0; q < JET; q++) z[q] = acc[jj][q];
      z[0] += bhl[g * 8 + jj];
      float o[JET];
      tanh_jet<JET>(z, o);
      x_write<JET, PTS>(ldsX, g * 8 + jj, p, o);
    }
    __syncthreads();
  }

  // ---- output layer: u = sum_k h[k] * Wout[k] + bo
  {
    float pacc[JET];
#pragma unroll
    for (int q = 0; q < JET; q++) pacc[q] = 0.0f;
    const float4* Wo = (const float4*)P.Wout;
    float4 wa = Wo[g * 2], wb = Wo[g * 2 + 1];
    float wv[8] = {wa.x, wa.y, wa.z, wa.w, wb.x, wb.y, wb.z, wb.w};
#pragma unroll
    for (int kk = 0; kk < 8; kk++) {
      float xv[JET];
      x_read<JET, PTS>(ldsX, g * 8 + kk, p, xv);
#pragma unroll
      for (int q = 0; q < JET; q++) pacc[q] = fmaf(wv[kk], xv[q], pacc[q]);
    }
    float* R = ldsW;  // reuse: [16][PTS][JET] <= 2560 floats < 4096
#pragma unroll
    for (int q = 0; q < JET; q++) R[(g * PTS + p) * JET + q] = pacc[q];
    __syncthreads();
    if (t < PTS * JET) {
      int pp = t % PTS, q = t / PTS;
      float s = 0.0f;
#pragma unroll
      for (int gg = 0; gg < 16; gg++) s += R[(gg * PTS + pp) * JET + q];
      if (q == 0) s += P.bo[0];
      U[pp * JET + q] = s;
    }
    __syncthreads();
  }
}

// ---------------- kernels ----------------
// ws layout (floats): [0,2048) res1 | [2048,4096) res2 | [4096,4352) bnd1 |
// [4352,4608) bnd2 | [4608, 4608+9*512) interface terms (term-major).
#define WS_RES1 0
#define WS_RES2 2048
#define WS_BND1 4096
#define WS_BND2 4352
#define WS_INTF 4608

__global__ void __launch_bounds__(256) residual_kernel(
    const float* xf1, const float* yf1, const float* ff1,
    const float* xf2, const float* yf2, const float* ff2,
    NetParams P1, NetParams P2, float* ws) {
  constexpr int JET = 5, PTS = 16;
  __shared__ __align__(16) float ldsX[H * PTS * JET];
  __shared__ __align__(16) float ldsW[4096];
  __shared__ float U[PTS * JET];
  __shared__ float T[PTS];
  const int t = threadIdx.x;
  const int p = t % PTS;
  const int net = blockIdx.y;
  const float* xs = net ? xf2 : xf1;
  const float* ys = net ? yf2 : yf1;
  const float* fs = net ? ff2 : ff1;
  NetParams P = net ? P2 : P1;
  const int base = blockIdx.x * PTS;
  float x = xs[base + p], y = ys[base + p];
  eval_net<JET, PTS>(P, x, y, ldsX, ldsW, U);
  if (t < PTS) {
    float f = U[t * JET + 2] + U[t * JET + 4] - fs[base + t];  // uxx+uyy-ff
    T[t] = f * f;
  }
  __syncthreads();
  if (t == 0) {
    float s = 0.0f;
#pragma unroll
    for (int i = 0; i < PTS; i++) s += T[i];
    ws[(net ? WS_RES2 : WS_RES1) + blockIdx.x] = s;
  }
}

// Boundary now reuses the SAME eval_net<5,16> instantiation as residual
// (the JET=1 instantiation blew up in codegen: 256 VGPR + ~8KB/thread
// scratch spill -> 3.2 GB of scratch traffic, 1353us). Derivative lanes
// are computed and discarded; 5x minimal FLOPs but minimal is ~15us.
__global__ void __launch_bounds__(256) boundary_kernel(
    const float* xb1, const float* yb1, const float* ub1,
    const float* xb2, const float* yb2, const float* ub2,
    NetParams P1, NetParams P2, float* ws) {
  constexpr int JET = 5, PTS = 16;
  __shared__ __align__(16) float ldsX[H * PTS * JET];
  __shared__ __align__(16) float ldsW[4096];
  __shared__ float U[PTS * JET];
  __shared__ float T[PTS];
  const int t = threadIdx.x;
  const int p = t % PTS;
  const int net = blockIdx.y;
  const float* xs = net ? xb2 : xb1;
  const float* ys = net ? yb2 : yb1;
  const float* us = net ? ub2 : ub1;
  NetParams P = net ? P2 : P1;
  const int base = blockIdx.x * PTS;
  float x = xs[base + p], y = ys[base + p];
  eval_net<JET, PTS>(P, x, y, ldsX, ldsW, U);
  if (t < PTS) {
    float d = us[base + t] - U[t * JET];   // value lane only
    T[t] = d * d;
  }
  __syncthreads();
  if (t == 0) {
    float s = 0.0f;
#pragma unroll
    for (int i = 0; i < PTS; i++) s += T[i];
    ws[(net ? WS_BND2 : WS_BND1) + blockIdx.x] = s;
  }
}

__global__ void __launch_bounds__(128) interface_kernel(
    const float* xi, const float* yi, const float* fi,
    NetParams P1, NetParams P2, float* ws) {
  constexpr int JET = 10, PTS = 8;
  __shared__ __align__(16) float ldsX[H * PTS * JET];
  __shared__ __align__(16) float ldsW[4096];
  __shared__ float U1[PTS * JET];
  __shared__ float U2[PTS * JET];
  __shared__ float T[PTS * 9];
  const int t = threadIdx.x;
  const int p = t % PTS;
  const int base = blockIdx.x * PTS;
  float x = xi[base + p], y = yi[base + p];
  eval_net<JET, PTS>(P1, x, y, ldsX, ldsW, U1);
  eval_net<JET, PTS>(P2, x, y, ldsX, ldsW, U2);
  if (t < PTS) {
    const float* a = U1 + t * JET;
    const float* b = U2 + t * JET;
    float fsrc = fi[base + t];
    float f1 = a[3] + a[5] - fsrc;           // v1xx+v1yy-fi
    float f2 = b[3] + b[5] - fsrc;
    float du = a[0] - b[0];
    float fd = f1 - f2;
    float dfl = a[2] - b[2];                 // v1y - v2y
    float g1x = a[6] + a[8], g1y = a[7] + a[9];
    float g2x = b[6] + b[8], g2y = b[7] + b[9];
    float dyy = a[5] - b[5];
    float dx  = a[1] - b[1];
    float dxx = a[3] - b[3];
    T[t * 9 + 0] = du * du;
    T[t * 9 + 1] = f1 * f1;
    T[t * 9 + 2] = f2 * f2;
    T[t * 9 + 3] = fd * fd;
    T[t * 9 + 4] = dfl * dfl;
    T[t * 9 + 5] = g1x * g1x + g1y * g1y + g2x * g2x + g2y * g2y;
    T[t * 9 + 6] = dyy * dyy;
    T[t * 9 + 7] = dx * dx;
    T[t * 9 + 8] = dxx * dxx;
  }
  __syncthreads();
  if (t < 9) {
    float s = 0.0f;
#pragma unroll
    for (int i = 0; i < PTS; i++) s += T[i * 9 + t];
    ws[WS_INTF + t * 512 + blockIdx.x] = s;
  }
}

__global__ void __launch_bounds__(256) combine_kernel(
    const float* ws, const float* iw, float* out) {
  __shared__ float red[256];
  __shared__ float sums[13];
  const int t = threadIdx.x;
  const int off[13] = {WS_RES1, WS_RES2, WS_BND1, WS_BND2,
                       WS_INTF + 0 * 512, WS_INTF + 1 * 512, WS_INTF + 2 * 512,
                       WS_INTF + 3 * 512, WS_INTF + 4 * 512, WS_INTF + 5 * 512,
                       WS_INTF + 6 * 512, WS_INTF + 7 * 512, WS_INTF + 8 * 512};
  const int len[13] = {2048, 2048, 256, 256, 512, 512, 512, 512, 512, 512, 512, 512, 512};
  for (int r = 0; r < 13; r++) {
    float s = 0.0f;
    for (int i = t; i < len[r]; i += 256) s += ws[off[r] + i];
    red[t] = s;
    __syncthreads();
    for (int w = 128; w > 0; w >>= 1) {
      if (t < w) red[t] += red[t + w];
      __syncthreads();
    }
    if (t == 0) sums[r] = red[0];
    __syncthreads();
  }
  if (t == 0) {
    const float Nf = 32768.0f, Nb = 4096.0f, Ni = 4096.0f;
    float mse_f  = (sums[0] + sums[1]) / Nf;
    float mse_ub = (sums[2] + sums[3]) / Nb;
    float su = sums[4];
    float mse_i_u    = su / Ni;
    float mse_i_uavg = su / (2.0f * Ni);
    float mse_i_res  = (sums[5] + sums[6]) / Ni;
    float mse_cont   = sums[7] / Ni;
    float mse_flux   = sums[8] / Ni;
    float mse_gres   = sums[9] / Ni;
    float mse_uyy    = sums[10] / Ni;
    float mse_ux     = sums[11] / Ni;
    float mse_uxx    = sums[12] / Ni;
    float il = iw[0] * mse_i_u + iw[1] * mse_i_uavg + iw[2] * mse_i_res
             + iw[3] * mse_cont + iw[4] * mse_flux + iw[6] * mse_gres
             + iw[5] * mse_uyy + iw[7] * mse_ux + iw[8] * mse_uxx;
    out[0] = 20.0f * mse_ub + mse_f + 5.0f * il;
  }
}

extern "C" void kernel_launch(void* const* d_in, const int* in_sizes, int n_in,
                              void* d_out, int out_size, void* d_ws, size_t ws_size,
                              hipStream_t stream) {
  const float* xb1 = (const float*)d_in[0];
  const float* yb1 = (const float*)d_in[1];
  const float* ub1 = (const float*)d_in[2];
  const float* xb2 = (const float*)d_in[3];
  const float* yb2 = (const float*)d_in[4];
  const float* ub2 = (const float*)d_in[5];
  const float* xf1 = (const float*)d_in[6];
  const float* yf1 = (const float*)d_in[7];
  const float* ff1 = (const float*)d_in[8];
  const float* xf2 = (const float*)d_in[9];
  const float* yf2 = (const float*)d_in[10];
  const float* ff2 = (const float*)d_in[11];
  const float* xi1 = (const float*)d_in[12];
  const float* yi1 = (const float*)d_in[13];
  const float* fi1 = (const float*)d_in[14];
  const float* iw  = (const float*)d_in[15];
  NetParams P1 = {(const float*)d_in[16], (const float*)d_in[17],
                  (const float*)d_in[18], (const float*)d_in[19],
                  (const float*)d_in[20], (const float*)d_in[21]};
  NetParams P2 = {(const float*)d_in[22], (const float*)d_in[23],
                  (const float*)d_in[24], (const float*)d_in[25],
                  (const float*)d_in[26], (const float*)d_in[27]};
  float* ws = (float*)d_ws;
  float* out = (float*)d_out;

  dim3 gridR(2048, 2);
  hipLaunchKernelGGL(residual_kernel, gridR, dim3(256), 0, stream,
                     xf1, yf1, ff1, xf2, yf2, ff2, P1, P2, ws);
  dim3 gridB(256, 2);
  hipLaunchKernelGGL(boundary_kernel, gridB, dim3(256), 0, stream,
                     xb1, yb1, ub1, xb2, yb2, ub2, P1, P2, ws);
  hipLaunchKernelGGL(interface_kernel, dim3(512), dim3(128), 0, stream,
                     xi1, yi1, fi1, P1, P2, ws);
  hipLaunchKernelGGL(combine_kernel, dim3(1), dim3(256), 0, stream,
                     ws, iw, out);
}